// Round 9
// baseline (37.452 us; speedup 1.0000x reference)
//
#include <hip/hip_runtime.h>
#include <math.h>

#define STEPN 16

typedef float v4f __attribute__((ext_vector_type(4)));

// ---- monotone key transform: uint min on keys == float min; max stored
// as inverted key so both partials reduce with min. No atomics anywhere.
__device__ __forceinline__ unsigned f2key(float f) {
    unsigned u = __float_as_uint(f);
    return u ^ ((u >> 31) ? 0xFFFFFFFFu : 0x80000000u);
}
__device__ __forceinline__ float key2f(unsigned k) {
    unsigned u = (k >> 31) ? (k ^ 0x80000000u) : ~k;
    return __uint_as_float(u);
}

// 256 blocks x 256 threads, 1 float4/thread (covers the 1 MB input exactly).
// Per-block partial min / ~max written as plain stores -> no memset node,
// no atomics, deterministic (fully rewritten every call).
__global__ __launch_bounds__(256) void pe_minmax_part(const v4f* __restrict__ in4,
                                                      unsigned* __restrict__ ws) {
    int gid = blockIdx.x * blockDim.x + threadIdx.x;
    v4f v = in4[gid];
    unsigned a = f2key(v.x), b = f2key(v.y), c = f2key(v.z), d = f2key(v.w);
    unsigned kmin  = min(min(a, b), min(c, d));
    unsigned kimax = ~max(max(a, b), max(c, d));
    #pragma unroll
    for (int off = 32; off > 0; off >>= 1) {
        kmin  = min(kmin,  (unsigned)__shfl_down((int)kmin,  off, 64));
        kimax = min(kimax, (unsigned)__shfl_down((int)kimax, off, 64));
    }
    __shared__ unsigned sm[8];
    int lane = threadIdx.x & 63, wid = threadIdx.x >> 6;
    if (lane == 0) { sm[wid * 2] = kmin; sm[wid * 2 + 1] = kimax; }
    __syncthreads();
    if (threadIdx.x == 0) {
        unsigned a0 = sm[0], b0 = sm[1];
        #pragma unroll
        for (int w = 1; w < 4; ++w) { a0 = min(a0, sm[w * 2]); b0 = min(b0, sm[w * 2 + 1]); }
        ws[blockIdx.x * 2]     = a0;
        ws[blockIdx.x * 2 + 1] = b0;
    }
}

// 16 elements/thread: wave covers 256 consecutive float4 of one plane
// (lane i owns base+i, +64, +128, +192) -> each t-plane write is 4 KB
// contiguous per wave (4 x 1 KB store instructions). Grid = 640 blocks,
// launch_bounds(256,4) -> VGPR <= 128 bin, 2-3 blocks/CU, no spills.
// 68 stores/wave ~ vmcnt depth: almost the whole stream can be in flight.
__global__ __launch_bounds__(256, 4) void pe_main(
        const v4f* __restrict__ in4,
        const unsigned* __restrict__ ws,
        const float* __restrict__ vth_p,
        float* __restrict__ out,
        int n_elem, int m, int np)
{
    const int n4  = n_elem >> 2;        // float4 per plane (65536)
    const int wpp = n4 >> 8;            // waves per plane (256)
    const int gid  = blockIdx.x * 256 + threadIdx.x;
    const int wave = gid >> 6;
    const int lane = gid & 63;
    const int neuron = wave / wpp;
    const int lw     = wave - neuron * wpp;
    const int fA = (lw << 8) + lane;    // float4 idx within plane

    // Issue input loads first: HBM latency hides under the partial-reduce.
    v4f x0 = in4[fA], x1 = in4[fA + 64], x2 = in4[fA + 128], x3 = in4[fA + 192];
    const float VTH = *vth_p;

    // ---- one wave reduces the np partial pairs, broadcasts via LDS ----
    __shared__ float sval[2];
    if (threadIdx.x < 64) {
        unsigned kmin = 0xFFFFFFFFu, kimax = 0xFFFFFFFFu;
        for (int i = threadIdx.x; i < np; i += 64) {
            kmin  = min(kmin,  ws[2 * i]);
            kimax = min(kimax, ws[2 * i + 1]);
        }
        #pragma unroll
        for (int off = 32; off > 0; off >>= 1) {
            kmin  = min(kmin,  (unsigned)__shfl_down((int)kmin,  off, 64));
            kimax = min(kimax, (unsigned)__shfl_down((int)kimax, off, 64));
        }
        if (threadIdx.x == 0) {
            sval[0] = key2f(kmin);
            sval[1] = key2f(~kimax);
        }
    }
    __syncthreads();
    const float Imin = sval[0];
    const float Imax = sval[1];

    // Replicate numpy fp32 rounding exactly: no FMA contraction.
    const float span  = __fdiv_rn(__fsub_rn(Imax, Imin), (float)(m - 2));
    const float c     = (float)(2 * neuron - 3) * 0.5f;            // exact
    const float mu    = __fadd_rn(Imin, __fmul_rn(c, span));
    const float sigma = __fdiv_rn(span, 1.5f);
    const float denom = __fmul_rn(__fmul_rn(2.0f, sigma), sigma);  // (2*sigma)*sigma

    float xs[16] = {x0.x, x0.y, x0.z, x0.w, x1.x, x1.y, x1.z, x1.w,
                    x2.x, x2.y, x2.z, x2.w, x3.x, x3.y, x3.z, x3.w};
    float dv[16];
    #pragma unroll
    for (int j = 0; j < 16; ++j) {
        float d = __fsub_rn(xs[j], mu);
        float q = __fdiv_rn(__fmul_rn(d, d), denom);
        dv[j] = (float)exp(-(double)q);   // correctly-rounded fp32 exp
    }

    float v[16], cnt[16];
    #pragma unroll
    for (int j = 0; j < 16; ++j) { v[j] = 0.f; cnt[j] = 0.f; }

    v4f* outp = (v4f*)out + (size_t)neuron * n4 + fA;
    const size_t tstride = (size_t)m * n4;

    #pragma unroll 2
    for (int t = 0; t < STEPN; ++t) {
        #pragma unroll
        for (int q4 = 0; q4 < 4; ++q4) {
            v4f sq;
            #pragma unroll
            for (int j = 0; j < 4; ++j) {
                int e = q4 * 4 + j;
                v[e] = __fadd_rn(v[e], dv[e]);
                float s = (v[e] >= VTH) ? 1.0f : 0.0f;
                v[e] = __fsub_rn(v[e], s * VTH);   // exact: s in {0,1}
                sq[j] = s;
                cnt[e] += s;
            }
            outp[q4 * 64] = sq;    // 4 x 1 KB -> 4 KB contiguous per wave
        }
        outp += tstride;
    }

    const float inv = 1.0f / (float)STEPN;   // exact
    #pragma unroll
    for (int q4 = 0; q4 < 4; ++q4) {
        v4f rq;
        #pragma unroll
        for (int j = 0; j < 4; ++j) rq[j] = cnt[q4 * 4 + j] * inv;
        outp[q4 * 64] = rq;
    }
}

extern "C" void kernel_launch(void* const* d_in, const int* in_sizes, int n_in,
                              void* d_out, int out_size, void* d_ws, size_t ws_size,
                              hipStream_t stream) {
    const float* inp = (const float*)d_in[0];
    const float* vth = (const float*)d_in[1];
    const int n_elem = in_sizes[0];                  // 262144
    const int m = out_size / ((STEPN + 1) * n_elem); // 10
    const int n4 = n_elem >> 2;                      // 65536

    unsigned* ws = (unsigned*)d_ws;
    float* out = (float*)d_out;

    const int rblocks = n4 / 256;                    // 256 partial blocks
    pe_minmax_part<<<rblocks, 256, 0, stream>>>((const v4f*)inp, ws);

    const int total_waves = m * (n4 >> 8);           // 2560
    const int mblocks = total_waves / 4;             // 640
    pe_main<<<mblocks, 256, 0, stream>>>((const v4f*)inp, ws, vth, out,
                                         n_elem, m, rblocks);
}

// Round 10
// 36.392 us; speedup vs baseline: 1.0291x; 1.0291x over previous
//
#include <hip/hip_runtime.h>
#include <math.h>

#define STEPN 16

typedef float v4f __attribute__((ext_vector_type(4)));

// ---- monotone key transform: uint min on keys == float min; max stored
// as inverted key so both partials reduce with min. No atomics anywhere.
__device__ __forceinline__ unsigned f2key(float f) {
    unsigned u = __float_as_uint(f);
    return u ^ ((u >> 31) ? 0xFFFFFFFFu : 0x80000000u);
}
__device__ __forceinline__ float key2f(unsigned k) {
    unsigned u = (k >> 31) ? (k ^ 0x80000000u) : ~k;
    return __uint_as_float(u);
}

// 64 blocks x 256 threads, 4 float4/thread. Per-block partial min / ~max
// written as plain stores -> no memset node, no atomics, deterministic.
__global__ __launch_bounds__(256) void pe_minmax_part(const v4f* __restrict__ in4,
                                                      unsigned* __restrict__ ws) {
    int gid = blockIdx.x * blockDim.x + threadIdx.x;
    unsigned kmin = 0xFFFFFFFFu, kimax = 0xFFFFFFFFu;
    #pragma unroll
    for (int r = 0; r < 4; ++r) {
        v4f v = in4[gid * 4 + r];
        unsigned a = f2key(v.x), b = f2key(v.y), c = f2key(v.z), d = f2key(v.w);
        kmin  = min(kmin,  min(min(a, b), min(c, d)));
        kimax = min(kimax, ~max(max(a, b), max(c, d)));
    }
    #pragma unroll
    for (int off = 32; off > 0; off >>= 1) {
        kmin  = min(kmin,  (unsigned)__shfl_down((int)kmin,  off, 64));
        kimax = min(kimax, (unsigned)__shfl_down((int)kimax, off, 64));
    }
    __shared__ unsigned sm[8];
    int lane = threadIdx.x & 63, wid = threadIdx.x >> 6;
    if (lane == 0) { sm[wid * 2] = kmin; sm[wid * 2 + 1] = kimax; }
    __syncthreads();
    if (threadIdx.x == 0) {
        unsigned a0 = sm[0], b0 = sm[1];
        #pragma unroll
        for (int w = 1; w < 4; ++w) { a0 = min(a0, sm[w * 2]); b0 = min(b0, sm[w * 2 + 1]); }
        ws[blockIdx.x * 2]     = a0;
        ws[blockIdx.x * 2 + 1] = b0;
    }
}

// 8 elements/thread, split-quad layout: lane i owns float4 (base+i) and
// (base+64+i) -> each t-step the wave stores 2 KB contiguous.
// Grid = 1280 blocks (exact: 5120 waves = 10 neurons x 512 waves/plane).
// R10: __syncthreads() each t-iteration re-syncs the block's 4 waves so the
// global write stream stays a coherent moving window per plane (fill-like
// DRAM row locality) instead of ~5000 drifting 2 KB streams.
__global__ __launch_bounds__(256, 5) void pe_main(
        const v4f* __restrict__ in4,
        const unsigned* __restrict__ ws,
        const float* __restrict__ vth_p,
        float* __restrict__ out,
        int n_elem, int m, int np)
{
    const int n4  = n_elem >> 2;        // float4 per plane (65536)
    const int wpp = n4 >> 7;            // waves per plane (512)
    const int gid  = blockIdx.x * 256 + threadIdx.x;
    const int wave = gid >> 6;
    const int lane = gid & 63;
    const int neuron = wave / wpp;
    const int lw     = wave - neuron * wpp;
    const int fA = (lw << 7) + lane;    // float4 idx within plane
    const int fB = fA + 64;

    // Issue input loads first: HBM latency hides under the partial-reduce.
    v4f xa = in4[fA], xb = in4[fB];
    const float VTH = *vth_p;

    // ---- one wave reduces the np partial pairs, broadcasts via LDS ----
    __shared__ float sval[2];
    if (threadIdx.x < 64) {
        unsigned kmin = 0xFFFFFFFFu, kimax = 0xFFFFFFFFu;
        for (int i = threadIdx.x; i < np; i += 64) {
            kmin  = min(kmin,  ws[2 * i]);
            kimax = min(kimax, ws[2 * i + 1]);
        }
        #pragma unroll
        for (int off = 32; off > 0; off >>= 1) {
            kmin  = min(kmin,  (unsigned)__shfl_down((int)kmin,  off, 64));
            kimax = min(kimax, (unsigned)__shfl_down((int)kimax, off, 64));
        }
        if (threadIdx.x == 0) {
            sval[0] = key2f(kmin);
            sval[1] = key2f(~kimax);
        }
    }
    __syncthreads();
    const float Imin = sval[0];
    const float Imax = sval[1];

    // Replicate numpy fp32 rounding exactly: no FMA contraction.
    const float span  = __fdiv_rn(__fsub_rn(Imax, Imin), (float)(m - 2));
    const float c     = (float)(2 * neuron - 3) * 0.5f;            // exact
    const float mu    = __fadd_rn(Imin, __fmul_rn(c, span));
    const float sigma = __fdiv_rn(span, 1.5f);
    const float denom = __fmul_rn(__fmul_rn(2.0f, sigma), sigma);  // (2*sigma)*sigma

    float xs[8] = {xa.x, xa.y, xa.z, xa.w, xb.x, xb.y, xb.z, xb.w};
    float dv[8];
    #pragma unroll
    for (int j = 0; j < 8; ++j) {
        float d = __fsub_rn(xs[j], mu);
        float q = __fdiv_rn(__fmul_rn(d, d), denom);
        dv[j] = (float)exp(-(double)q);   // correctly-rounded fp32 exp
    }

    float v[8]   = {0.f,0.f,0.f,0.f,0.f,0.f,0.f,0.f};
    float cnt[8] = {0.f,0.f,0.f,0.f,0.f,0.f,0.f,0.f};

    v4f* outp = (v4f*)out + (size_t)neuron * n4 + fA;
    const size_t tstride = (size_t)m * n4;

    #pragma unroll 4
    for (int t = 0; t < STEPN; ++t) {
        __syncthreads();   // re-sync the block's write streams each plane
        v4f sa, sb;
        #pragma unroll
        for (int j = 0; j < 4; ++j) {
            v[j] = __fadd_rn(v[j], dv[j]);
            float s = (v[j] >= VTH) ? 1.0f : 0.0f;
            v[j] = __fsub_rn(v[j], s * VTH);   // exact: s in {0,1}
            sa[j] = s;
            cnt[j] += s;
        }
        #pragma unroll
        for (int j = 4; j < 8; ++j) {
            v[j] = __fadd_rn(v[j], dv[j]);
            float s = (v[j] >= VTH) ? 1.0f : 0.0f;
            v[j] = __fsub_rn(v[j], s * VTH);
            sb[j - 4] = s;
            cnt[j] += s;
        }
        outp[0]  = sa;    // 2 KB contiguous per wave per t-step
        outp[64] = sb;
        outp += tstride;
    }

    const float inv = 1.0f / (float)STEPN;   // exact
    v4f ra, rb;
    #pragma unroll
    for (int j = 0; j < 4; ++j) { ra[j] = cnt[j] * inv; rb[j] = cnt[j + 4] * inv; }
    outp[0]  = ra;
    outp[64] = rb;
}

extern "C" void kernel_launch(void* const* d_in, const int* in_sizes, int n_in,
                              void* d_out, int out_size, void* d_ws, size_t ws_size,
                              hipStream_t stream) {
    const float* inp = (const float*)d_in[0];
    const float* vth = (const float*)d_in[1];
    const int n_elem = in_sizes[0];                  // 262144
    const int m = out_size / ((STEPN + 1) * n_elem); // 10
    const int n4 = n_elem >> 2;                      // 65536

    unsigned* ws = (unsigned*)d_ws;
    float* out = (float*)d_out;

    const int rblocks = 64;                          // 64 partial pairs
    pe_minmax_part<<<rblocks, 256, 0, stream>>>((const v4f*)inp, ws);

    const int total_threads = m * (n4 >> 7) * 64;    // 327680
    const int mblocks = total_threads / 256;         // 1280
    pe_main<<<mblocks, 256, 0, stream>>>((const v4f*)inp, ws, vth, out,
                                         n_elem, m, rblocks);
}